// Round 1
// 424.389 us; speedup vs baseline: 1.0309x; 1.0309x over previous
//
#include <hip/hip_runtime.h>
#include <float.h>

// Top-left corner pooling, fused: out = 2 * rev_cummax_W(rev_cummax_H(x))
// x: (16, 256, 128, 128) fp32 NCHW -> 4096 independent 128x128 planes.
//
// Round-3 change: chunked H-scan. Round 2 was latency-bound, not BW-bound:
// only 2048 waves (2/SIMD) each with a 128-iteration dependent loop and
// <=4 loads in flight -> ~19% of achievable HBM BW. Plane-level parallelism
// is exhausted, so we decompose the H suffix-scan:
//   - one block (512 thr = 16 lane-groups) owns one 128x128 plane
//   - group g owns rows [8g, 8g+8), kept ENTIRELY in registers (8 x float4)
//   - phase 1: 8 independent loads, per-chunk column-max -> LDS
//   - barrier; carry[g] = max of colmax over chunks > g (H suffix carry)
//   - phase 2: descending scan over the 8 register rows seeded with carry,
//     then the (verified, unchanged) per-row DPP W-scan, store.
// => 32768 waves (4-8/SIMD), 8-deep MLP per wave, still exactly 1R+1W of HBM.
//
// DPP scan notes (unchanged from Round 2): lanes are REVERSED vs columns
// (lane j holds vector index 31-j) so the column suffix-max is a lane
// prefix-max; the row_shr/row_bcast15 idiom is segmented at 32 lanes, so the
// two chunks sharing a wave64 never mix; exclusive prefix via wave_shr:1 is
// killed at each 32-lane segment start (lane 32 must not read lane 31).

#define DPP_ROW_SHR1 0x111
#define DPP_ROW_SHR2 0x112
#define DPP_ROW_SHR4 0x114
#define DPP_ROW_SHR8 0x118
#define DPP_ROW_BCAST15 0x142
#define DPP_WAVE_SHR1 0x138

template <int CTRL, int ROW_MASK>
__device__ __forceinline__ float dpp_mov_f(float src) {
  // old = -FLT_MAX: lanes with no valid source (or rows masked off) get the
  // max-identity, so fmaxf(x, dpp(...)) is a no-op there.
  const int old = (int)0xFF7FFFFFu;  // bit pattern of -FLT_MAX
  int r = __builtin_amdgcn_update_dpp(old, __builtin_bit_cast(int, src),
                                      CTRL, ROW_MASK, 0xF, false);
  return __builtin_bit_cast(float, r);
}

__global__ __launch_bounds__(512) void corner_pool_kernel(
    const float* __restrict__ x, float* __restrict__ out, int planes) {
  constexpr int H = 128;
  constexpr int W = 128;
  constexpr int WV = W / 4;      // float4s per row = 32
  constexpr int NCHUNK = 16;     // lane-groups per block = chunks per plane
  constexpr int ROWS = H / NCHUNK;  // 8 rows per chunk, held in registers

  __shared__ float4 colmax_lds[NCHUNK * WV];  // 8 KiB

  const int plane = blockIdx.x;
  if (plane >= planes) return;

  const int lane32 = threadIdx.x & 31;
  const int g = threadIdx.x >> 5;  // chunk id 0..15 (rows [8g, 8g+8))
  const int rv = 31 - lane32;      // reversed vector index within the row
  const int h0 = g * ROWS;

  const float4* __restrict__ xin = (const float4*)(x + (size_t)plane * H * W);
  float4* __restrict__ yout = (float4*)(out + (size_t)plane * H * W);

  const float NINF = -FLT_MAX;

  // ---- Phase 1: load the chunk's 8 rows (independent loads -> deep MLP),
  //      reduce to per-chunk column max.
  float4 row[ROWS];
#pragma unroll
  for (int i = 0; i < ROWS; ++i) row[i] = xin[(h0 + i) * WV + rv];

  float4 cmax = make_float4(NINF, NINF, NINF, NINF);
#pragma unroll
  for (int i = 0; i < ROWS; ++i) {
    cmax.x = fmaxf(cmax.x, row[i].x);
    cmax.y = fmaxf(cmax.y, row[i].y);
    cmax.z = fmaxf(cmax.z, row[i].z);
    cmax.w = fmaxf(cmax.w, row[i].w);
  }
  colmax_lds[g * WV + rv] = cmax;
  __syncthreads();

  // ---- Carry: column max of all chunks BELOW this one (h suffix, exclusive).
  float4 carry = make_float4(NINF, NINF, NINF, NINF);
  for (int c = g + 1; c < NCHUNK; ++c) {
    float4 t = colmax_lds[c * WV + rv];
    carry.x = fmaxf(carry.x, t.x);
    carry.y = fmaxf(carry.y, t.y);
    carry.z = fmaxf(carry.z, t.z);
    carry.w = fmaxf(carry.w, t.w);
  }

  // ---- Phase 2: descending H-scan over register rows, DPP W-scan, store.
  float4 cm = carry;
  const bool seg_start = (lane32 == 0);

#pragma unroll
  for (int i = ROWS - 1; i >= 0; --i) {
    // H-direction running suffix max (per column, loop-carried)
    cm.x = fmaxf(cm.x, row[i].x);
    cm.y = fmaxf(cm.y, row[i].y);
    cm.z = fmaxf(cm.z, row[i].z);
    cm.w = fmaxf(cm.w, row[i].w);

    // Intra-lane suffix max over ascending columns x..w
    float mw = cm.w;
    float mz = fmaxf(cm.z, mw);
    float my = fmaxf(cm.y, mz);
    float mx = fmaxf(cm.x, my);  // lane max M

    // Inclusive lane-prefix max over the 32-lane segment (pure VALU DPP)
    float gg = mx;
    gg = fmaxf(gg, dpp_mov_f<DPP_ROW_SHR1, 0xF>(gg));
    gg = fmaxf(gg, dpp_mov_f<DPP_ROW_SHR2, 0xF>(gg));
    gg = fmaxf(gg, dpp_mov_f<DPP_ROW_SHR4, 0xF>(gg));
    gg = fmaxf(gg, dpp_mov_f<DPP_ROW_SHR8, 0xF>(gg));
    // rows 1 & 3 pick up lane 15 / lane 47 totals -> segmented at 32
    gg = fmaxf(gg, dpp_mov_f<DPP_ROW_BCAST15, 0xA>(gg));

    // Exclusive prefix: shift inclusive by one lane across the wave,
    // then kill the value at each 32-lane segment start.
    float e = dpp_mov_f<DPP_WAVE_SHR1, 0xF>(gg);
    e = seg_start ? NINF : e;

    float4 r;
    r.x = gg;  // == max(mx, e)
    r.y = fmaxf(my, e);
    r.z = fmaxf(mz, e);
    r.w = fmaxf(mw, e);

    // out = y + y
    r.x += r.x;
    r.y += r.y;
    r.z += r.z;
    r.w += r.w;
    yout[(h0 + i) * WV + rv] = r;
  }
}

extern "C" void kernel_launch(void* const* d_in, const int* in_sizes, int n_in,
                              void* d_out, int out_size, void* d_ws,
                              size_t ws_size, hipStream_t stream) {
  const float* x = (const float*)d_in[0];
  float* out = (float*)d_out;

  const int plane_elems = 128 * 128;
  const int planes = in_sizes[0] / plane_elems;  // 4096

  const int block = 512;       // 16 lane-groups = 16 chunks = 1 plane/block
  const int grid = planes;     // 4096 blocks -> 32768 waves

  corner_pool_kernel<<<grid, block, 0, stream>>>(x, out, planes);
}